// Round 4
// baseline (269.662 us; speedup 1.0000x reference)
//
#include <hip/hip_runtime.h>
#include <stdint.h>
#include <math.h>

// Problem constants (B=8192 rows, D=512 features)
#define Bn 8192
#define Dn 512
#define EPSN 1e-12f
#define EPSP 1e-6f
#define MARG 0.3f

// GEMM structure (R4): each block owns 64 rows x full K=512 of A in LDS
// (staged once -> ONE barrier in the whole K path, no per-iter vmcnt(0)
// drain), and streams B fragments directly global->VGPR with a 2-deep
// software pipeline. 4 waves each compute 64 rows x 64 cols (acc 4x4).
#define RS 64            // rows per block
#define CS 256           // cols per block
#define KT2 16           // 512 / 32 k-steps
#define NCT2 (Bn / CS)   // 32 column tiles
#define NRS (Bn / RS)    // 128 row strips

typedef short bf16x8 __attribute__((ext_vector_type(8)));  // 8 bf16 (4 VGPRs)
typedef float f32x4  __attribute__((ext_vector_type(4)));

__device__ __forceinline__ uint16_t f2bf(float f) {
    union { float f; uint32_t u; } c; c.f = f;
    uint32_t r = (c.u + 0x7fffu + ((c.u >> 16) & 1u)) >> 16;  // RNE
    return (uint16_t)r;
}

// async global->LDS, 16B per lane; LDS dest is wave-uniform base + lane*16
__device__ __forceinline__ void async16(const void* g, void* l) {
    __builtin_amdgcn_global_load_lds(
        (const __attribute__((address_space(1))) void*)g,
        (__attribute__((address_space(3))) void*)l,
        16, 0, 0);
}

// ---------------------------------------------------------------------------
// K1: per-row L2 normalize -> bf16 rows, inverse norms, and column term
// c[j] = -sp2[j] + 2*eps*sp[j]. One wave per 512-float row, 16384 rows.
// ---------------------------------------------------------------------------
__global__ __launch_bounds__(256) void k_normalize(
    const float* __restrict__ x,
    uint16_t* __restrict__ a_bf, uint16_t* __restrict__ p_bf,
    float* __restrict__ rnA, float* __restrict__ rnP,
    float* __restrict__ cterm)
{
    const int wave = threadIdx.x >> 6;
    const int lane = threadIdx.x & 63;
    const int r = blockIdx.x * 4 + wave;   // 0..16383
    const int i = r >> 1;
    const int which = r & 1;               // 0 = a-row, 1 = p-row

    const float* src = x + (size_t)i * (2 * Dn) + (size_t)which * Dn + lane * 8;
    float4 lo = ((const float4*)src)[0];
    float4 hi = ((const float4*)src)[1];
    float v[8] = {lo.x, lo.y, lo.z, lo.w, hi.x, hi.y, hi.z, hi.w};

    float ss = 0.f;
#pragma unroll
    for (int j = 0; j < 8; ++j) ss += v[j] * v[j];
#pragma unroll
    for (int m = 1; m < 64; m <<= 1) ss += __shfl_xor(ss, m);
    const float scale = 1.0f / fmaxf(sqrtf(ss), EPSN);

    float o[8], s1 = 0.f, s2 = 0.f;
#pragma unroll
    for (int j = 0; j < 8; ++j) { o[j] = v[j] * scale; s1 += o[j]; s2 += o[j] * o[j]; }

    uint16_t* bdst = (which ? p_bf : a_bf) + (size_t)i * Dn + lane * 8;
    bf16x8 bb;
#pragma unroll
    for (int j = 0; j < 8; ++j) bb[j] = (short)f2bf(o[j]);
    *(bf16x8*)bdst = bb;

    if (which) {
#pragma unroll
        for (int m = 1; m < 64; m <<= 1) { s1 += __shfl_xor(s1, m); s2 += __shfl_xor(s2, m); }
        if (lane == 0) { cterm[i] = -s2 + 2.0f * EPSP * s1; rnP[i] = scale; }
    } else {
        if (lane == 0) rnA[i] = scale;
    }
}

// ---------------------------------------------------------------------------
// K2: barrier-free-K-loop GEMM + fused per-row argmax.
// A strip (64 x 512, 64 KB) staged once via global_load_lds, XOR-swizzled
// 16B chunks: chunk (row, slot) holds global chunk slot ^ (row&7), so each
// 16-lane read phase spreads over all 8 bank groups (R3-verified criterion).
// B fragments stream global->VGPR, 2-deep rotating prefetch, no barriers ->
// compiler emits fine-grained vmcnt(N) instead of vmcnt(0) drains.
// Supertile swizzle: 64 consecutive blocks = 8 coltiles x 8 rowstrips so the
// concurrent B working set (~2 MB) fits per-XCD L2.
// ---------------------------------------------------------------------------
__global__ __launch_bounds__(256, 2) void k_gemm_argmax(
    const uint16_t* __restrict__ a_bf, const uint16_t* __restrict__ p_bf,
    const float* __restrict__ cterm,
    float* __restrict__ pval, int* __restrict__ pidx)
{
    __shared__ uint16_t As[RS * Dn];   // 64 KB
    __shared__ float rv[4][RS];
    __shared__ int   ri[4][RS];

    // supertile decode
    const int bid = blockIdx.x;
    const int sup = bid >> 6;              // 0..63
    const int w   = bid & 63;
    const int ct  = (sup & 3) * 8 + (w & 7);    // coltile 0..31
    const int rs  = (sup >> 2) * 8 + (w >> 3);  // rowstrip 0..127
    const int rowBase = rs * RS;
    const int colBase = ct * CS;

    const int t = threadIdx.x;
    const int wave = t >> 6;
    const int lane = t & 63;
    const int q = lane >> 4;       // 0..3  (k-chunk within 32)
    const int m16 = lane & 15;
    const int m7 = m16 & 7;

    // ---- stage full A strip (4096 16B chunks, 16 per thread)
#pragma unroll
    for (int s = 0; s < 16; ++s) {
        const int c = s * 256 + t;          // chunk id; row uniform per wave
        const int row = c >> 6;
        const int slot = c & 63;
        const int gch = slot ^ (row & 7);   // involution swizzle
        const uint16_t* g = a_bf + (size_t)(rowBase + row) * Dn + gch * 8;
        async16(g, &As[(size_t)c * 8]);
    }

    f32x4 acc[4][4];
#pragma unroll
    for (int a = 0; a < 4; ++a)
#pragma unroll
        for (int b = 0; b < 4; ++b) acc[a][b] = (f32x4){0.f, 0.f, 0.f, 0.f};

    // per-lane B gather pointers: col n = m16, k-chunk q (4 lanes/row read
    // one contiguous 64B segment)
    const uint16_t* pb[4];
#pragma unroll
    for (int nt = 0; nt < 4; ++nt) {
        const int col = colBase + wave * 64 + nt * 16 + m16;
        pb[nt] = p_bf + (size_t)col * Dn + q * 8;
    }

    __syncthreads();   // the ONLY pre-epilogue barrier: A strip resident

    // rotating 3-stage B pipeline, prefetch distance 2
    bf16x8 bb[3][4];
#pragma unroll
    for (int nt = 0; nt < 4; ++nt) bb[0][nt] = *(const bf16x8*)(pb[nt]);
#pragma unroll
    for (int nt = 0; nt < 4; ++nt) bb[1][nt] = *(const bf16x8*)(pb[nt] + 32);

#pragma unroll
    for (int kt = 0; kt < KT2; ++kt) {
        if (kt + 2 < KT2) {
#pragma unroll
            for (int nt = 0; nt < 4; ++nt)
                bb[(kt + 2) % 3][nt] = *(const bf16x8*)(pb[nt] + (kt + 2) * 32);
        }
        bf16x8 af[4];
        const int slot = (kt * 4 + q) ^ m7;
#pragma unroll
        for (int mt = 0; mt < 4; ++mt) {
            const int row = mt * 16 + m16;
            af[mt] = *(const bf16x8*)(&As[row * Dn + slot * 8]);
        }
#pragma unroll
        for (int mt = 0; mt < 4; ++mt)
#pragma unroll
            for (int nt = 0; nt < 4; ++nt)
                acc[mt][nt] = __builtin_amdgcn_mfma_f32_16x16x32_bf16(
                    af[mt], bb[kt % 3][nt], acc[mt][nt], 0, 0, 0);
    }

    // epilogue: score = 2*dot + c[j]; mask diagonal; per-row argmax over the
    // wave's 64-col slice, then combine 4 slices via LDS.
    float cv[4];
#pragma unroll
    for (int nt = 0; nt < 4; ++nt)
        cv[nt] = cterm[colBase + wave * 64 + nt * 16 + m16];

#pragma unroll
    for (int mt = 0; mt < 4; ++mt) {
#pragma unroll
        for (int v = 0; v < 4; ++v) {
            const int lr = mt * 16 + q * 4 + v;     // C/D row = quad*4+reg
            const int gi = rowBase + lr;
            float best = -INFINITY;
            int bidx = 0x7fffffff;
#pragma unroll
            for (int nt = 0; nt < 4; ++nt) {
                const int gj = colBase + wave * 64 + nt * 16 + m16; // col=lane&15
                float sc = 2.0f * acc[mt][nt][v] + cv[nt];
                if (gj == gi) sc = -INFINITY;
                if (sc > best || (sc == best && gj < bidx)) { best = sc; bidx = gj; }
            }
#pragma unroll
            for (int msk = 1; msk < 16; msk <<= 1) {
                float ob = __shfl_xor(best, msk);
                int oi = __shfl_xor(bidx, msk);
                if (ob > best || (ob == best && oi < bidx)) { best = ob; bidx = oi; }
            }
            if (m16 == 0) { rv[wave][lr] = best; ri[wave][lr] = bidx; }
        }
    }
    __syncthreads();
    if (t < RS) {
        float b0 = rv[0][t]; int i0 = ri[0][t];
#pragma unroll
        for (int ww = 1; ww < 4; ++ww) {
            float b1 = rv[ww][t]; int i1 = ri[ww][t];
            if (b1 > b0 || (b1 == b0 && i1 < i0)) { b0 = b1; i0 = i1; }
        }
        const size_t o = (size_t)(rowBase + t) * NCT2 + ct;
        pval[o] = b0;
        pidx[o] = i0;
    }
}

// ---------------------------------------------------------------------------
// K3: reduce 32 partials -> negidx; recompute normalized rows from x and the
// stored inverse norms; pos/neg distances elementwise in fp32 per reference.
// One wave per row.
// ---------------------------------------------------------------------------
__global__ __launch_bounds__(256) void k_rowloss(
    const float* __restrict__ x,
    const float* __restrict__ rnA, const float* __restrict__ rnP,
    const float* __restrict__ pval, const int* __restrict__ pidx,
    float* __restrict__ rowloss)
{
    const int wave = threadIdx.x >> 6;
    const int lane = threadIdx.x & 63;
    const int i = blockIdx.x * 4 + wave;

    // lanes 32..63 duplicate lanes 0..31 (harmless under max w/ same index)
    float best = pval[(size_t)i * NCT2 + (lane & 31)];
    int bidx = pidx[(size_t)i * NCT2 + (lane & 31)];
#pragma unroll
    for (int msk = 1; msk < 32; msk <<= 1) {
        float ob = __shfl_xor(best, msk);
        int oi = __shfl_xor(bidx, msk);
        if (ob > best || (ob == best && oi < bidx)) { best = ob; bidx = oi; }
    }

    const float ra = rnA[i];
    const float rp = rnP[i];
    const float rn = rnP[bidx];
    const float4* av = (const float4*)(x + (size_t)i * (2 * Dn));
    const float4* pv = (const float4*)(x + (size_t)i * (2 * Dn) + Dn);
    const float4* nv = (const float4*)(x + (size_t)bidx * (2 * Dn) + Dn);
    float pos = 0.f, ng = 0.f;
#pragma unroll
    for (int c = 0; c < 2; ++c) {
        const int idx = lane + c * 64;
        float4 a4 = av[idx], p4 = pv[idx], n4 = nv[idx];
        float u;
        u = a4.x * ra - p4.x * rp + EPSP; pos += u * u;
        u = a4.y * ra - p4.y * rp + EPSP; pos += u * u;
        u = a4.z * ra - p4.z * rp + EPSP; pos += u * u;
        u = a4.w * ra - p4.w * rp + EPSP; pos += u * u;
        u = a4.x * ra - n4.x * rn + EPSP; ng += u * u;
        u = a4.y * ra - n4.y * rn + EPSP; ng += u * u;
        u = a4.z * ra - n4.z * rn + EPSP; ng += u * u;
        u = a4.w * ra - n4.w * rn + EPSP; ng += u * u;
    }
#pragma unroll
    for (int msk = 1; msk < 64; msk <<= 1) {
        pos += __shfl_xor(pos, msk);
        ng += __shfl_xor(ng, msk);
    }
    if (lane == 0) rowloss[i] = fmaxf(pos - ng + MARG, 0.f);
}

// ---------------------------------------------------------------------------
// K4: mean over 8192 row losses -> scalar out (deterministic)
// ---------------------------------------------------------------------------
__global__ __launch_bounds__(1024) void k_final(
    const float* __restrict__ rowloss, float* __restrict__ out)
{
    __shared__ float sm[16];
    float s = 0.f;
    for (int k = threadIdx.x; k < Bn; k += 1024) s += rowloss[k];
#pragma unroll
    for (int msk = 1; msk < 64; msk <<= 1) s += __shfl_xor(s, msk);
    if ((threadIdx.x & 63) == 0) sm[threadIdx.x >> 6] = s;
    __syncthreads();
    if (threadIdx.x == 0) {
        float tot = 0.f;
#pragma unroll
        for (int w = 0; w < 16; ++w) tot += sm[w];
        out[0] = tot * (1.0f / Bn);
    }
}

extern "C" void kernel_launch(void* const* d_in, const int* in_sizes, int n_in,
                              void* d_out, int out_size, void* d_ws, size_t ws_size,
                              hipStream_t stream)
{
    const float* x = (const float*)d_in[0];
    char* ws = (char*)d_ws;
    // workspace layout (bytes):
    uint16_t* a_bf    = (uint16_t*)(ws + 0);         // 8 MB
    uint16_t* p_bf    = (uint16_t*)(ws + 8388608);   // 8 MB
    float*    rnA     = (float*)(ws + 16777216);     // 32 KB
    float*    rnP     = (float*)(ws + 16809984);     // 32 KB
    float*    cterm   = (float*)(ws + 16842752);     // 32 KB
    float*    pval    = (float*)(ws + 16875520);     // 1 MB
    int*      pidx    = (int*)(ws + 17924096);       // 1 MB
    float*    rowloss = (float*)(ws + 18972672);     // 32 KB  (total ~19 MB)
    float*    out     = (float*)d_out;

    k_normalize<<<4096, 256, 0, stream>>>(x, a_bf, p_bf, rnA, rnP, cterm);
    k_gemm_argmax<<<NRS * NCT2, 256, 0, stream>>>(a_bf, p_bf, cterm, pval, pidx);
    k_rowloss<<<2048, 256, 0, stream>>>(x, rnA, rnP, pval, pidx, rowloss);
    k_final<<<1, 1024, 0, stream>>>(rowloss, out);
}